// Round 8
// baseline (2895.360 us; speedup 1.0000x reference)
//
#include <hip/hip_runtime.h>
#include <hip/hip_bf16.h>

#define B_  64
#define T_  512
#define I_  64
#define H_  1024
#define O_  64

typedef __bf16 bf16x8 __attribute__((ext_vector_type(8)));
typedef unsigned short u16x8 __attribute__((ext_vector_type(8)));
typedef float f32x4 __attribute__((ext_vector_type(4)));
typedef unsigned int u32;
typedef unsigned long long u64;

static __device__ __forceinline__ f32x4 mfma16(bf16x8 a, bf16x8 b, f32x4 c) {
  return __builtin_amdgcn_mfma_f32_16x16x32_bf16(a, b, c, 0, 0, 0);
}

// 8 consecutive aligned f32 -> bf16x8
static __device__ __forceinline__ bf16x8 cvt8(const float* __restrict__ p) {
  f32x4 v0 = *(const f32x4*)p;
  f32x4 v1 = *(const f32x4*)(p + 4);
  bf16x8 r;
  r[0] = (__bf16)v0[0]; r[1] = (__bf16)v0[1];
  r[2] = (__bf16)v0[2]; r[3] = (__bf16)v0[3];
  r[4] = (__bf16)v1[0]; r[5] = (__bf16)v1[1];
  r[6] = (__bf16)v1[2]; r[7] = (__bf16)v1[3];
  return r;
}

static __device__ __forceinline__ u32 pack_bf16x2(float a, float b) {
  unsigned short lo = __builtin_bit_cast(unsigned short, (__bf16)a);
  unsigned short hi = __builtin_bit_cast(unsigned short, (__bf16)b);
  return (u32)lo | ((u32)hi << 16);
}
static __device__ __forceinline__ int imin(int a, int b) { return a < b ? a : b; }

// Self-validating write-once encoding: stored word = bits(v)+1 with v>=0
// (relu) => word in [1, 0x7F800002], so bit31==0 and word!=0. Valid iff
// (int)word > 0. Backgrounds: 0x00000000 (memset) fails >0; 0xAAAAAAAA
// (poison) has bit31=1 => signed negative, fails. Every polled address is
// written exactly once per launch => no stale-generation ambiguity (no ABA).

// ---------------- recurrence: 32 blocks = 4 batch-groups x 8 col-slices
// 512 threads = 8 waves; wave owns 16 cols; block owns 128 cols.
// Single barrier per step (LDS double-buffer); own slice bypasses global.
__global__ void __launch_bounds__(512) k_rec(
    const float* __restrict__ x, const float* __restrict__ h0,
    const float* __restrict__ Wih, const float* __restrict__ Whh,
    const float* __restrict__ bih, const float* __restrict__ bhh,
    float* __restrict__ hidden_out)
{
  __shared__ unsigned short hlds[2 * 16 * 1024];   // 64KB double-buffered

  const int bid = blockIdx.x;
  const int g = bid >> 3;            // batch group 0..3 (16 batches)
  const int j = bid & 7;             // col slice 0..7 (128 cols)
  const int tid = threadIdx.x;
  const int wv = tid >> 6;           // wave 0..7 -> 16-col subtile
  const int l  = tid & 63;
  const int l4 = l >> 4, lm = l & 15;

  const int nrow = j * 128 + wv * 16 + lm;   // output neuron (B row / C col)
  const int ab   = g * 16 + lm;              // global batch (A row)

  // W_hh^T B-fragments, resident in the unified VGPR/AGPR file.
  u16x8 bw[32];
  #pragma unroll
  for (int kk = 0; kk < 32; ++kk)
    bw[kk] = __builtin_bit_cast(u16x8, cvt8(Whh + nrow * H_ + kk * 32 + l4 * 8));
  u16x8 bwi0 = __builtin_bit_cast(u16x8, cvt8(Wih + nrow * I_ + 0  + l4 * 8));
  u16x8 bwi1 = __builtin_bit_cast(u16x8, cvt8(Wih + nrow * I_ + 32 + l4 * 8));
  const float bias = bih[nrow] + bhh[nrow];

  // staging role: thread covers batch-row lrow; chunk c = 4 f32 cols at
  // col c*128 + q*4  (chunk index c == producer slice index!)
  const int lrow = tid >> 5;          // 0..15 (batch within group)
  const int q    = tid & 31;          // 32 threads per row

  const int sw_w = (lrow & 7) << 4;   // write-side XOR swizzle
  const u32 want = 0xFFu;             // all 8 chunks
  const u32 own  = 1u << j;           // own slice pre-satisfied (from LDS path)

  for (int s = 1; s <= T_; ++s) {
    char* ldsc = (char*)hlds + (size_t)(s & 1) * 32768;        // current buf

    // ---- x loads (independent; issue first)
    const float* xr = x + ((size_t)ab * T_ + (s - 1)) * I_ + l4 * 8;
    f32x4 xv0 = *(const f32x4*)xr;
    f32x4 xv1 = *(const f32x4*)(xr + 4);
    f32x4 y0  = *(const f32x4*)(xr + 32);
    f32x4 y1  = *(const f32x4*)(xr + 36);

    // ---- stage h_{s-1} into LDS[s&1] as bf16
    if (s == 1) {
      const float* hp = h0 + (size_t)(g * 16 + lrow) * H_ + q * 4;
      #pragma unroll
      for (int c = 0; c < 8; ++c) {
        f32x4 v = *(const f32x4*)(hp + c * 128);
        u32 p0 = pack_bf16x2(v[0], v[1]);
        u32 p1 = pack_bf16x2(v[2], v[3]);
        int off = (lrow * 2048 + (c * 128 + q * 4) * 2) ^ sw_w;
        *(u64*)(ldsc + off) = (u64)p0 | ((u64)p1 << 32);
      }
    } else {
      // per-chunk self-validating poll of the encoded f32 history (write-once)
      const u64* basep = (const u64*)(hidden_out +
          ((size_t)(g * 16 + lrow) * T_ + (s - 2)) * H_) + q * 2;
      u32 vmask = own;
      do {
        u32 prev = vmask;
        #pragma unroll
        for (int c = 0; c < 8; ++c) {
          if (vmask & (1u << c)) continue;
          u64 w0 = __hip_atomic_load(basep + c * 64 + 0, __ATOMIC_RELAXED,
                                     __HIP_MEMORY_SCOPE_AGENT);
          u64 w1 = __hip_atomic_load(basep + c * 64 + 1, __ATOMIC_RELAXED,
                                     __HIP_MEMORY_SCOPE_AGENT);
          int m = imin(imin((int)(u32)w0, (int)(u32)(w0 >> 32)),
                       imin((int)(u32)w1, (int)(u32)(w1 >> 32)));
          if (m > 0) {
            vmask |= 1u << c;
            u32 a0 = (u32)w0 - 1u, a1 = (u32)(w0 >> 32) - 1u;
            u32 a2 = (u32)w1 - 1u, a3 = (u32)(w1 >> 32) - 1u;
            u32 p0 = pack_bf16x2(__builtin_bit_cast(float, a0),
                                 __builtin_bit_cast(float, a1));
            u32 p1 = pack_bf16x2(__builtin_bit_cast(float, a2),
                                 __builtin_bit_cast(float, a3));
            int off = (lrow * 2048 + (c * 128 + q * 4) * 2) ^ sw_w;
            *(u64*)(ldsc + off) = (u64)p0 | ((u64)p1 << 32);
          }
        }
        if (vmask == prev) __builtin_amdgcn_s_sleep(1);   // throttle when stalled
      } while (vmask != want);
    }
    __syncthreads();   // the ONLY barrier per step

    // ---- x-projection (K = I = 64)
    f32x4 accx = {0.f, 0.f, 0.f, 0.f};
    {
      bf16x8 xa0, xa1;
      xa0[0]=(__bf16)xv0[0]; xa0[1]=(__bf16)xv0[1]; xa0[2]=(__bf16)xv0[2]; xa0[3]=(__bf16)xv0[3];
      xa0[4]=(__bf16)xv1[0]; xa0[5]=(__bf16)xv1[1]; xa0[6]=(__bf16)xv1[2]; xa0[7]=(__bf16)xv1[3];
      xa1[0]=(__bf16)y0[0]; xa1[1]=(__bf16)y0[1]; xa1[2]=(__bf16)y0[2]; xa1[3]=(__bf16)y0[3];
      xa1[4]=(__bf16)y1[0]; xa1[5]=(__bf16)y1[1]; xa1[6]=(__bf16)y1[2]; xa1[7]=(__bf16)y1[3];
      accx = mfma16(xa0, __builtin_bit_cast(bf16x8, bwi0), accx);
      accx = mfma16(xa1, __builtin_bit_cast(bf16x8, bwi1), accx);
    }

    // ---- recurrent GEMM from LDS (A row = lm, k = kk*32 + l4*8 + e)
    f32x4 a0 = {0,0,0,0}, a1 = {0,0,0,0}, a2 = {0,0,0,0}, a3 = {0,0,0,0};
    #pragma unroll
    for (int kk = 0; kk < 32; kk += 4) {
      int base = lm * 2048 + l4 * 16;
      int sw = (lm & 7) << 4;
      u16x8 h0v = *(const u16x8*)(ldsc + ((base + (kk + 0) * 64) ^ sw));
      u16x8 h1v = *(const u16x8*)(ldsc + ((base + (kk + 1) * 64) ^ sw));
      u16x8 h2v = *(const u16x8*)(ldsc + ((base + (kk + 2) * 64) ^ sw));
      u16x8 h3v = *(const u16x8*)(ldsc + ((base + (kk + 3) * 64) ^ sw));
      a0 = mfma16(__builtin_bit_cast(bf16x8, h0v), __builtin_bit_cast(bf16x8, bw[kk + 0]), a0);
      a1 = mfma16(__builtin_bit_cast(bf16x8, h1v), __builtin_bit_cast(bf16x8, bw[kk + 1]), a1);
      a2 = mfma16(__builtin_bit_cast(bf16x8, h2v), __builtin_bit_cast(bf16x8, bw[kk + 2]), a2);
      a3 = mfma16(__builtin_bit_cast(bf16x8, h3v), __builtin_bit_cast(bf16x8, bw[kk + 3]), a3);
    }
    f32x4 acc = (a0 + a1) + (a2 + a3) + accx;

    // ---- epilogue: own C-tile -> next LDS buffer (bf16) + encoded global
    // stores (the inter-block signal). Safe to write LDS[(s+1)&1] here:
    // barrier-s proved all waves completed step s-1, its last reader.
    char* ldsn = (char*)hlds + (size_t)((s + 1) & 1) * 32768;
    #pragma unroll
    for (int r = 0; r < 4; ++r) {
      int b2 = l4 * 4 + r;                     // C/D: row=(l>>4)*4+r
      float v = acc[r] + bias;
      v = v > 0.f ? v : 0.f;
      int off = (b2 * 2048 + nrow * 2) ^ ((b2 & 7) << 4);
      *(unsigned short*)(ldsn + off) = __builtin_bit_cast(unsigned short, (__bf16)v);
      u32 e = __builtin_bit_cast(u32, v) + 1u;
      __hip_atomic_store((u32*)hidden_out +
                         ((size_t)(g * 16 + b2) * T_ + (s - 1)) * H_ + nrow,
                         e, __ATOMIC_RELAXED, __HIP_MEMORY_SCOPE_AGENT);
    }
  }
}

// ---------------- output projection + h_last copy (hidden holds encoded
// values, +1 ulp on f32 ~1e-7 relative — far below tolerance, no decode)
__global__ void __launch_bounds__(256) k_out(
    const float* __restrict__ hidden, const float* __restrict__ Wout,
    const float* __restrict__ bout, float* __restrict__ out,
    float* __restrict__ hlast)
{
  int idx = blockIdx.x * 256 + threadIdx.x;
  for (int i = idx; i < B_ * H_; i += gridDim.x * 256)
    hlast[i] = hidden[(size_t)(i >> 10) * (T_ * H_) + (size_t)(T_ - 1) * H_ + (i & (H_ - 1))];

  const int wv = threadIdx.x >> 6;
  const int l  = threadIdx.x & 63;
  const int l4 = l >> 4, lm = l & 15;
  const int rt = blockIdx.x * 4 + wv;      // row tile (16 bt-rows)
  const int rowA = rt * 16 + lm;

  f32x4 acc0 = {0,0,0,0}, acc1 = {0,0,0,0}, acc2 = {0,0,0,0}, acc3 = {0,0,0,0};
  float bo0 = bout[0 * 16 + lm], bo1 = bout[1 * 16 + lm];
  float bo2 = bout[2 * 16 + lm], bo3 = bout[3 * 16 + lm];

  #pragma unroll
  for (int kk = 0; kk < 32; ++kk) {
    bf16x8 a = cvt8(hidden + (size_t)rowA * H_ + kk * 32 + l4 * 8);
    acc0 = mfma16(a, cvt8(Wout + (size_t)(0 * 16 + lm) * H_ + kk * 32 + l4 * 8), acc0);
    acc1 = mfma16(a, cvt8(Wout + (size_t)(1 * 16 + lm) * H_ + kk * 32 + l4 * 8), acc1);
    acc2 = mfma16(a, cvt8(Wout + (size_t)(2 * 16 + lm) * H_ + kk * 32 + l4 * 8), acc2);
    acc3 = mfma16(a, cvt8(Wout + (size_t)(3 * 16 + lm) * H_ + kk * 32 + l4 * 8), acc3);
  }

  #pragma unroll
  for (int r = 0; r < 4; ++r) {
    int row = rt * 16 + l4 * 4 + r;
    out[(size_t)row * O_ + 0 * 16 + lm] = acc0[r] + bo0;
    out[(size_t)row * O_ + 1 * 16 + lm] = acc1[r] + bo1;
    out[(size_t)row * O_ + 2 * 16 + lm] = acc2[r] + bo2;
    out[(size_t)row * O_ + 3 * 16 + lm] = acc3[r] + bo3;
  }
}

extern "C" void kernel_launch(void* const* d_in, const int* in_sizes, int n_in,
                              void* d_out, int out_size, void* d_ws, size_t ws_size,
                              hipStream_t stream) {
  const float* x    = (const float*)d_in[0];
  const float* h0   = (const float*)d_in[1];
  const float* Wih  = (const float*)d_in[2];
  const float* Whh  = (const float*)d_in[3];
  const float* bih  = (const float*)d_in[4];
  const float* bhh  = (const float*)d_in[5];
  const float* Wout = (const float*)d_in[6];
  const float* bout = (const float*)d_in[7];

  float* out = (float*)d_out;
  float* hidden_out  = out;                                   // [B,T,H]
  float* output_list = out + (size_t)B_ * T_ * H_;            // [B,T,O]
  float* hlast       = output_list + (size_t)B_ * T_ * O_;    // [1,B,H]

  k_rec<<<32, 512, 0, stream>>>(x, h0, Wih, Whh, bih, bhh, hidden_out);
  k_out<<<512, 256, 0, stream>>>(hidden_out, Wout, bout, output_list, hlast);
}